// Round 1
// baseline (113.008 us; speedup 1.0000x reference)
//
#include <hip/hip_runtime.h>
#include <hip/hip_bf16.h>

// Problem constants (match reference)
#define B_  8
#define L_  512
#define C_  6
#define N_  (B_ * L_)
#define K_  9
#define BIGF 1e10f

// Output layout (flat float32, concatenated in return order)
#define NK        (N_ * K_)               // 36864
#define OFF_DKNN  0
#define OFF_SRC   (NK)                    // 36864
#define OFF_DST   (2 * NK)                // 73728
#define OFF_VALID (3 * NK)                // 110592
#define OFF_GLB   (4 * NK)                // 147456
#define GLB_PER   (2 * L_ - 1)            // 1023
#define GLB_TOT   (2 * B_ * GLB_PER)      // 16368
#define OFF_SEQ   (OFF_GLB + GLB_TOT)     // 163824
#define SEQ_PER   (2 * (L_ - 2))          // 1020
#define SEQ_TOT   (2 * B_ * SEQ_PER)      // 16320

static __device__ __forceinline__ unsigned long long umin64(unsigned long long a,
                                                            unsigned long long b) {
    return a < b ? a : b;
}

// Static edge lists: glb_edges [2, B*(2L-1)], seq_edges [2, B*2(L-2)]
__global__ void edges_kernel(float* __restrict__ out) {
    int t = blockIdx.x * blockDim.x + threadIdx.x;
    if (t < GLB_TOT) {
        int r = t / (B_ * GLB_PER);
        int rem = t % (B_ * GLB_PER);
        int b = rem / GLB_PER;
        int q = rem % GLB_PER;
        int v;
        if (r == 0) v = (q < L_) ? 0 : (q - (L_ - 1));   // src: [0]*L ++ [1..L-1]
        else        v = (q < L_) ? q : 0;                // dst: [0..L-1] ++ [0]*(L-1)
        out[OFF_GLB + t] = (float)(v + b * L_);
    }
    if (t < SEQ_TOT) {
        int r = t / (B_ * SEQ_PER);
        int rem = t % (B_ * SEQ_PER);
        int b = rem / SEQ_PER;
        int q = rem % SEQ_PER;
        int v;
        if (r == 0) v = (q < L_ - 2) ? (q + 1) : (q - (L_ - 2) + 2);  // [1..510] ++ [2..511]
        else        v = (q < L_ - 2) ? (q + 2) : (q - (L_ - 2) + 1);  // [2..511] ++ [1..510]
        out[OFF_SEQ + t] = (float)(v + b * L_);
    }
}

// One block per row i (global node). 256 threads; each handles 2 columns.
__global__ __launch_bounds__(256) void knn_kernel(const float* __restrict__ X,
                                                  const int* __restrict__ AP,
                                                  const int* __restrict__ S,
                                                  const int* __restrict__ sec,
                                                  float* __restrict__ out) {
#pragma clang fp contract(off)
    const int row = blockIdx.x;          // 0..N_-1
    const int b = row >> 9;              // L_ = 512
    const int tid = threadIdx.x;

    __shared__ float xi[C_][3];
    __shared__ float sqi[C_];
    __shared__ int   padi_s;             // bitmask of padded channels of row i
    __shared__ int   glbi_s;
    __shared__ float dist[L_];
    __shared__ unsigned long long red[256];
    __shared__ int   sel_idx[K_];
    __shared__ float sel_val[K_];

    if (tid < C_ * 3) xi[tid / 3][tid % 3] = X[(size_t)row * (C_ * 3) + tid];
    if (tid == 0) {
        glbi_s = (S[row] == 0);
        int m = 0;
        for (int c = 0; c < C_; ++c)
            if (AP[row * C_ + c] == 0) m |= (1 << c);
        padi_s = m;
    }
    __syncthreads();
    if (tid < C_) {
        float x = xi[tid][0], y = xi[tid][1], z = xi[tid][2];
        sqi[tid] = (x * x + y * y) + z * z;   // matches jnp.sum(X*X, -1) order
    }
    __syncthreads();

    const int padi = padi_s;
    const int glbi = glbi_s;
    const bool row_has_nonpad = (padi != 0x3F);

    for (int jj = tid; jj < L_; jj += 256) {
        const int col = b * L_ + jj;
        const float* Xj = X + (size_t)col * (C_ * 3);
        float xj[C_][3], sqj[C_];
        int padj = 0;
        for (int d = 0; d < C_; ++d) {
            float x = Xj[d * 3 + 0], y = Xj[d * 3 + 1], z = Xj[d * 3 + 2];
            xj[d][0] = x; xj[d][1] = y; xj[d][2] = z;
            sqj[d] = (x * x + y * y) + z * z;
            if (AP[col * C_ + d] == 0) padj |= (1 << d);
        }
        const int glbj = (S[col] == 0);
        const bool any = row_has_nonpad && (padj != 0x3F);

        float m = 3.0e38f;
        for (int c = 0; c < C_; ++c) {
            const float a0 = xi[c][0], a1 = xi[c][1], a2 = xi[c][2];
            const float sc = sqi[c];
            const bool ci = ((padi >> c) & 1) == 0;
            for (int d = 0; d < C_; ++d) {
                const bool ok = ci && (((padj >> d) & 1) == 0);
                float dot = ((a0 * xj[d][0]) + (a1 * xj[d][1])) + (a2 * xj[d][2]);
                float d2 = (sc + sqj[d]) - 2.0f * dot;
                m = fminf(m, ok ? d2 : 3.0e38f);
            }
        }
        float dval;
        if (glbi || glbj || !any) dval = BIGF;
        else                      dval = sqrtf(fmaxf(m, 0.0f));
        dist[jj] = dval;
    }
    __syncthreads();

    // 9 rounds of stable argmin (val asc, tie -> lower index), top_k semantics
    for (int t = 0; t < K_; ++t) {
        unsigned long long best = ~0ull;
        for (int jj = tid; jj < L_; jj += 256) {
            unsigned int fb = __float_as_uint(dist[jj]);  // dist >= 0: bits order = float order
            best = umin64(best, ((unsigned long long)fb << 32) | (unsigned int)jj);
        }
        red[tid] = best;
        __syncthreads();
        for (int s = 128; s > 0; s >>= 1) {
            if (tid < s) red[tid] = umin64(red[tid], red[tid + s]);
            __syncthreads();
        }
        if (tid == 0) {
            unsigned long long k0 = red[0];
            int idx = (int)(k0 & 0xFFFFFFFFu);
            sel_idx[t] = idx;
            sel_val[t] = __uint_as_float((unsigned int)(k0 >> 32));
            dist[idx] = 3.3e38f;   // exclude from later rounds
        }
        __syncthreads();
    }

    if (tid < K_) {
        const int idx = sel_idx[tid];
        const float v = sel_val[tid];
        const int dstg = b * L_ + idx;
        const bool valid = (v < BIGF) && (sec[row] == sec[dstg]);
        const size_t o = (size_t)row * K_ + tid;
        out[OFF_DKNN + o]  = v;
        out[OFF_SRC + o]   = (float)row;
        out[OFF_DST + o]   = valid ? (float)dstg : -1.0f;
        out[OFF_VALID + o] = valid ? 1.0f : 0.0f;
    }
}

extern "C" void kernel_launch(void* const* d_in, const int* in_sizes, int n_in,
                              void* d_out, int out_size, void* d_ws, size_t ws_size,
                              hipStream_t stream) {
    (void)in_sizes; (void)n_in; (void)out_size; (void)d_ws; (void)ws_size;
    const float* X   = (const float*)d_in[0];
    const int*   AP  = (const int*)d_in[1];
    const int*   S   = (const int*)d_in[2];
    const int*   sec = (const int*)d_in[3];
    float* out = (float*)d_out;

    hipLaunchKernelGGL(edges_kernel, dim3((GLB_TOT + 255) / 256), dim3(256), 0, stream, out);
    hipLaunchKernelGGL(knn_kernel, dim3(N_), dim3(256), 0, stream, X, AP, S, sec, out);
}

// Round 2
// 103.276 us; speedup vs baseline: 1.0942x; 1.0942x over previous
//
#include <hip/hip_runtime.h>

// Problem constants (match reference)
#define B_  8
#define L_  512
#define C_  6
#define N_  (B_ * L_)
#define K_  9
#define BIGF 1e10f

// Output layout (flat float32, concatenated in return order)
#define NK        (N_ * K_)               // 36864
#define OFF_DKNN  0
#define OFF_SRC   (NK)
#define OFF_DST   (2 * NK)
#define OFF_VALID (3 * NK)
#define OFF_GLB   (4 * NK)
#define GLB_PER   (2 * L_ - 1)            // 1023
#define GLB_TOT   (2 * B_ * GLB_PER)      // 16368
#define OFF_SEQ   (OFF_GLB + GLB_TOT)
#define SEQ_PER   (2 * (L_ - 2))          // 1020
#define SEQ_TOT   (2 * B_ * SEQ_PER)      // 16320

#define PK 24   // packed floats per node: 18 coords + 6 biased sq (96 B, 16B-aligned)

typedef unsigned long long ull;

// Prep: repack X into 16B-aligned records with pad/global masks folded into sq,
// plus write the static glb/seq edge lists.
__global__ __launch_bounds__(256) void prep_kernel(const float* __restrict__ X,
                                                   const int* __restrict__ AP,
                                                   const int* __restrict__ S,
                                                   float* __restrict__ packed,
                                                   float* __restrict__ out) {
    const int t = blockIdx.x * blockDim.x + threadIdx.x;
    if (t < N_) {
        const float bias_g = (S[t] == 0) ? BIGF : 0.0f;
        float* p = packed + (size_t)t * PK;
        const float* x = X + (size_t)t * 18;
#pragma unroll
        for (int c = 0; c < C_; ++c) {
            const float a = x[c * 3], b = x[c * 3 + 1], d = x[c * 3 + 2];
            p[c * 3] = a; p[c * 3 + 1] = b; p[c * 3 + 2] = d;
            float sq = (a * a + b * b) + d * d;
            if (AP[t * C_ + c] == 0) sq += BIGF;   // padded channel loses every min
            p[18 + c] = sq + bias_g;               // global node loses every min
        }
    }
    if (t < GLB_TOT) {
        const int r = t / (B_ * GLB_PER);
        const int rem = t % (B_ * GLB_PER);
        const int b = rem / GLB_PER;
        const int q = rem % GLB_PER;
        int v;
        if (r == 0) v = (q < L_) ? 0 : (q - (L_ - 1));   // src: [0]*L ++ [1..L-1]
        else        v = (q < L_) ? q : 0;                // dst: [0..L-1] ++ [0]*(L-1)
        out[OFF_GLB + t] = (float)(v + b * L_);
    }
    if (t < SEQ_TOT) {
        const int r = t / (B_ * SEQ_PER);
        const int rem = t % (B_ * SEQ_PER);
        const int b = rem / SEQ_PER;
        const int q = rem % SEQ_PER;
        int v;
        if (r == 0) v = (q < L_ - 2) ? (q + 1) : (q - (L_ - 2) + 2);  // [1..510]++[2..511]
        else        v = (q < L_ - 2) ? (q + 2) : (q - (L_ - 2) + 1);  // [2..511]++[1..510]
        out[OFF_SEQ + t] = (float)(v + b * L_);
    }
}

// One WAVE per row. 4 waves (256 threads) per block, no LDS, no barriers.
// Lane j owns columns {j, 64+j, ..., 448+j}. Selection = 9 rounds of
// wave-wide u64 argmin via shfl_xor butterfly (stable: tie -> lower col).
__global__ __launch_bounds__(256) void knn_kernel(const float* __restrict__ packed,
                                                  const int* __restrict__ sec,
                                                  float* __restrict__ out) {
    const int lane = threadIdx.x & 63;
    const int wv = threadIdx.x >> 6;
    const int row = blockIdx.x * 4 + wv;
    const int base = row & ~(L_ - 1);

    // Row record -> registers
    float ri[PK];
    {
        const float4* p4 = (const float4*)(packed + (size_t)row * PK);
#pragma unroll
        for (int i = 0; i < 6; ++i) {
            const float4 q = p4[i];
            ri[4 * i] = q.x; ri[4 * i + 1] = q.y; ri[4 * i + 2] = q.z; ri[4 * i + 3] = q.w;
        }
    }

    ull v[8];
#pragma unroll
    for (int s = 0; s < 8; ++s) {
        const int col = s * 64 + lane;
        float cb[PK];
        {
            const float4* p4 = (const float4*)(packed + (size_t)(base + col) * PK);
#pragma unroll
            for (int i = 0; i < 6; ++i) {
                const float4 q = p4[i];
                cb[4 * i] = q.x; cb[4 * i + 1] = q.y; cb[4 * i + 2] = q.z; cb[4 * i + 3] = q.w;
            }
        }
        float m = 3.0e38f;
#pragma unroll
        for (int c = 0; c < C_; ++c) {
            const float a0 = ri[c * 3], a1 = ri[c * 3 + 1], a2 = ri[c * 3 + 2];
            const float sc = ri[18 + c];
#pragma unroll
            for (int d = 0; d < C_; ++d) {
                const float dot = a0 * cb[d * 3] + a1 * cb[d * 3 + 1] + a2 * cb[d * 3 + 2];
                const float s2 = sc + cb[18 + d];
                const float d2 = fmaf(-2.0f, dot, s2);
                m = fminf(m, d2);
            }
        }
        // valid pairs: d2 <= ~8e3;  any masked term pushes past 1e9
        const float dval = (m < 1.0e9f) ? sqrtf(fmaxf(m, 0.0f)) : BIGF;
        v[s] = ((ull)__float_as_uint(dval) << 32) | (unsigned)col;  // dval>=0: bit order == value order
    }

    // 9 stable argmin rounds, all in-wave
    ull w[K_];
#pragma unroll
    for (int t = 0; t < K_; ++t) {
        ull loc = v[0];
#pragma unroll
        for (int s = 1; s < 8; ++s) loc = (v[s] < loc) ? v[s] : loc;
#pragma unroll
        for (int off = 32; off >= 1; off >>= 1) {
            const ull o = (ull)__shfl_xor((unsigned long long)loc, off, 64);
            loc = (o < loc) ? o : loc;
        }
        w[t] = loc;                                  // every lane has round-t winner
        const int wc = (int)(loc & 0xFFFFFFFFu);
        if (lane == (wc & 63)) v[wc >> 6] = ~0ull;   // owner removes it
    }

    if (lane < K_) {
        ull mine = w[0];
#pragma unroll
        for (int t = 1; t < K_; ++t) mine = (lane == t) ? w[t] : mine;
        const int col = (int)(mine & 0xFFFFFFFFu);
        const float dval = __uint_as_float((unsigned)(mine >> 32));
        const int dst = base + col;
        const bool valid = (dval < BIGF) && (sec[row] == sec[dst]);
        const size_t o = (size_t)row * K_ + lane;
        out[OFF_DKNN + o]  = dval;
        out[OFF_SRC + o]   = (float)row;
        out[OFF_DST + o]   = valid ? (float)dst : -1.0f;
        out[OFF_VALID + o] = valid ? 1.0f : 0.0f;
    }
}

extern "C" void kernel_launch(void* const* d_in, const int* in_sizes, int n_in,
                              void* d_out, int out_size, void* d_ws, size_t ws_size,
                              hipStream_t stream) {
    (void)in_sizes; (void)n_in; (void)out_size; (void)ws_size;
    const float* X   = (const float*)d_in[0];
    const int*   AP  = (const int*)d_in[1];
    const int*   S   = (const int*)d_in[2];
    const int*   sec = (const int*)d_in[3];
    float* out = (float*)d_out;
    float* packed = (float*)d_ws;     // N_*PK*4 = 384 KiB

    hipLaunchKernelGGL(prep_kernel, dim3((GLB_TOT + 255) / 256), dim3(256), 0, stream,
                       X, AP, S, packed, out);
    hipLaunchKernelGGL(knn_kernel, dim3(N_ / 4), dim3(256), 0, stream,
                       packed, sec, out);
}

// Round 3
// 72.956 us; speedup vs baseline: 1.5490x; 1.4156x over previous
//
#include <hip/hip_runtime.h>

// Problem constants (match reference)
#define B_  8
#define L_  512
#define C_  6
#define N_  (B_ * L_)
#define K_  9
#define BIGF 1e10f

// Output layout (flat float32, concatenated in return order)
#define NK        (N_ * K_)               // 36864
#define OFF_DKNN  0
#define OFF_SRC   (NK)
#define OFF_DST   (2 * NK)
#define OFF_VALID (3 * NK)
#define OFF_GLB   (4 * NK)
#define GLB_PER   (2 * L_ - 1)            // 1023
#define GLB_TOT   (2 * B_ * GLB_PER)      // 16368
#define OFF_SEQ   (OFF_GLB + GLB_TOT)
#define SEQ_PER   (2 * (L_ - 2))          // 1020
#define SEQ_TOT   (2 * B_ * SEQ_PER)      // 16320

#define TPB 512            // 8 waves = 8 rows per block
#define RPB 8

static __device__ __forceinline__ unsigned umin32(unsigned a, unsigned b) {
    return a < b ? a : b;
}

// One fused kernel. Block = one graph slice: preps all 512 nodes of its graph
// into LDS (coords + pad/global-biased |x|^2 per channel), then each of the 8
// waves computes one row's 512 distances from LDS and selects top-9 in-wave
// on 32-bit quantized keys. Static edge lists written by the first blocks.
__global__ __launch_bounds__(TPB, 4) void fused_kernel(const float* __restrict__ X,
                                                       const int* __restrict__ AP,
                                                       const int* __restrict__ S,
                                                       const int* __restrict__ sec,
                                                       float* __restrict__ out) {
    __shared__ float4 ch[C_][L_];   // per channel: (x, y, z, sq + masks)  = 48 KB

    const int tid = threadIdx.x;
    const int lane = tid & 63;
    const int wv = tid >> 6;
    const int row = blockIdx.x * RPB + wv;
    const int base = row & ~(L_ - 1);
    const int rl = row & (L_ - 1);

    // ---- static glb/seq edge lists (first 32 blocks' threads) ----
    {
        const int gt = blockIdx.x * TPB + tid;
        if (gt < GLB_TOT) {
            const int r = gt / (B_ * GLB_PER);
            const int rem = gt % (B_ * GLB_PER);
            const int b = rem / GLB_PER;
            const int q = rem % GLB_PER;
            int v;
            if (r == 0) v = (q < L_) ? 0 : (q - (L_ - 1));   // src: [0]*L ++ [1..L-1]
            else        v = (q < L_) ? q : 0;                // dst: [0..L-1] ++ [0]*(L-1)
            out[OFF_GLB + gt] = (float)(v + b * L_);
        }
        if (gt < SEQ_TOT) {
            const int r = gt / (B_ * SEQ_PER);
            const int rem = gt % (B_ * SEQ_PER);
            const int b = rem / SEQ_PER;
            const int q = rem % SEQ_PER;
            int v;
            if (r == 0) v = (q < L_ - 2) ? (q + 1) : (q - (L_ - 2) + 2);  // [1..510]++[2..511]
            else        v = (q < L_ - 2) ? (q + 2) : (q - (L_ - 2) + 1);  // [2..511]++[1..510]
            out[OFF_SEQ + gt] = (float)(v + b * L_);
        }
    }

    // ---- prep: thread t packs node (base+t) of this block's graph into LDS ----
    {
        const int node = base + tid;
        const float* x = X + (size_t)node * (C_ * 3);
        const float bias_g = (S[node] == 0) ? BIGF : 0.0f;
#pragma unroll
        for (int c = 0; c < C_; ++c) {
            const float a = x[c * 3], b = x[c * 3 + 1], d = x[c * 3 + 2];
            float sq = (a * a + b * b) + d * d;
            if (AP[node * C_ + c] == 0) sq += BIGF;  // padded channel loses every min
            ch[c][tid] = make_float4(a, b, d, sq + bias_g);
        }
    }
    __syncthreads();

    // ---- row fragment: broadcast-read own record, fold -2 into coords ----
    float ax[C_], ay[C_], az[C_], sc[C_];
#pragma unroll
    for (int c = 0; c < C_; ++c) {
        const float4 q = ch[c][rl];
        ax[c] = -2.0f * q.x; ay[c] = -2.0f * q.y; az[c] = -2.0f * q.z;
        sc[c] = q.w;
    }

    // ---- distances: lane j owns cols {j, 64+j, ..., 448+j} ----
    unsigned v[8];
#pragma unroll
    for (int s = 0; s < 8; ++s) {
        const int col = s * 64 + lane;
        float m = 3.0e38f;
#pragma unroll
        for (int d = 0; d < C_; ++d) {
            const float4 q = ch[d][col];
            float md = 3.0e38f;
#pragma unroll
            for (int c = 0; c < C_; ++c) {
                const float val = fmaf(az[c], q.z, fmaf(ay[c], q.y, fmaf(ax[c], q.x, sc[c])));
                md = fminf(md, val);
            }
            m = fminf(m, md + q.w);
        }
        m = fmaxf(m, 0.0f);   // d2, clamped; masked pairs land >= ~1e10
        // 23-bit value prefix + 9-bit col: u32 order == (d2, col) lexicographic
        v[s] = (__float_as_uint(m) & 0xFFFFFE00u) | (unsigned)col;
    }

    // ---- 9 rounds of stable wave argmin on u32 keys ----
    unsigned mine = 0xFFFFFFFFu;
#pragma unroll
    for (int t = 0; t < K_; ++t) {
        unsigned loc = v[0];
#pragma unroll
        for (int s = 1; s < 8; ++s) loc = umin32(loc, v[s]);
#pragma unroll
        for (int off = 32; off >= 1; off >>= 1) {
            const unsigned o = (unsigned)__shfl_xor((int)loc, off, 64);
            loc = umin32(loc, o);
        }
        if (lane == t) mine = loc;                 // lane t keeps round-t winner
#pragma unroll
        for (int s = 0; s < 8; ++s)                // remove winner (keys unique)
            v[s] = (v[s] == loc) ? 0xFFFFFFFFu : v[s];
    }

    // ---- epilogue: lanes 0..8 write the 4 per-edge outputs ----
    if (lane < K_) {
        const int col = (int)(mine & 511u);
        const float d2 = __uint_as_float(mine & 0xFFFFFE00u);
        const bool masked = (d2 >= 1.0e9f);        // valid pairs are < ~1e5
        const float dval = masked ? BIGF : sqrtf(d2);
        const int dst = base + col;
        const bool valid = !masked && (sec[row] == sec[dst]);
        const size_t o = (size_t)row * K_ + lane;
        out[OFF_DKNN + o]  = dval;
        out[OFF_SRC + o]   = (float)row;
        out[OFF_DST + o]   = valid ? (float)dst : -1.0f;
        out[OFF_VALID + o] = valid ? 1.0f : 0.0f;
    }
}

extern "C" void kernel_launch(void* const* d_in, const int* in_sizes, int n_in,
                              void* d_out, int out_size, void* d_ws, size_t ws_size,
                              hipStream_t stream) {
    (void)in_sizes; (void)n_in; (void)out_size; (void)d_ws; (void)ws_size;
    const float* X   = (const float*)d_in[0];
    const int*   AP  = (const int*)d_in[1];
    const int*   S   = (const int*)d_in[2];
    const int*   sec = (const int*)d_in[3];
    float* out = (float*)d_out;

    hipLaunchKernelGGL(fused_kernel, dim3(N_ / RPB), dim3(TPB), 0, stream,
                       X, AP, S, sec, out);
}